// Round 7
// baseline (478.709 us; speedup 1.0000x reference)
//
#include <hip/hip_runtime.h>
#include <math.h>

typedef unsigned short u16;
typedef unsigned int   u32;
typedef short bf16x8 __attribute__((ext_vector_type(8)));
typedef float f32x4  __attribute__((ext_vector_type(4)));
typedef u16 u16x8 __attribute__((ext_vector_type(8)));
typedef u32 u32x4 __attribute__((ext_vector_type(4)));

#define MFMA16(a,b,c) __builtin_amdgcn_mfma_f32_16x16x32_bf16((a),(b),(c),0,0,0)

__device__ __forceinline__ float bf2f(u16 h){ u32 u=((u32)h)<<16; return __uint_as_float(u); }
__device__ __forceinline__ u16 f2bf(float f){ u32 u=__float_as_uint(f); return (u16)((u+0x7fffu+((u>>16)&1u))>>16); }
__device__ __forceinline__ u32 pack2(float a, float b){ return (u32)f2bf(a) | ((u32)f2bf(b)<<16); }

// async global->LDS, 16B/lane. LDS dest is wave-uniform base + lane*16 (m97 pattern).
__device__ __forceinline__ void gl2lds(const u16* g, u16* l){
  __builtin_amdgcn_global_load_lds((const __attribute__((address_space(1))) u32*)g,
                                   (__attribute__((address_space(3))) u32*)l, 16, 0, 0);
}
__device__ __forceinline__ void stc(u16* p, float v){ *p = f2bf(v); }
__device__ __forceinline__ void stc(float* p, float v){ *p = v; }
__device__ __forceinline__ void ld4(const u16* p, float* v){ ushort4 x=*(const ushort4*)p; v[0]=bf2f(x.x);v[1]=bf2f(x.y);v[2]=bf2f(x.z);v[3]=bf2f(x.w); }

// XCD-aware bijective block remap (T1, m204 form). Requires nwg % 8 == 0.
__device__ __forceinline__ int xcd_remap(){
  int gx = gridDim.x, gy = gridDim.y;
  int lin = blockIdx.x + gx*(blockIdx.y + gy*blockIdx.z);
  int nwg = gx*gy*gridDim.z;
  if (nwg & 7) return lin;
  int q = nwg >> 3;
  return (lin & 7)*q + (lin >> 3);
}

// ---- prep: cvt weights to bf16 + zero norms (one dispatch) ----
__global__ void prep_kernel(const float* __restrict__ qkv_w, const float* __restrict__ proj_w,
                            u16* __restrict__ wq, u16* __restrict__ wp, float* __restrict__ norms){
  int i = blockIdx.x*256 + threadIdx.x;
  if (i < 110592) wq[i] = f2bf(qkv_w[i]);
  else if (i < 147456) wp[i-110592] = f2bf(proj_w[i-110592]);
  else if (i < 156672) norms[i-147456] = 0.f;
}

// ---- tiled transpose: in [z][192][in_pitch] (u16) -> out [z][cols][192] bf16 ----
__global__ __launch_bounds__(256) void transpose_kernel(
    const u16* __restrict__ in, u16* __restrict__ out,
    long in_hi, long in_lo, long out_slab, int in_pitch)
{
  __shared__ float tile[64][65];
  const int t = threadIdx.x;
  const int z = blockIdx.z;
  const u16* ip = in + (long)(z>>3)*in_hi + (long)(z&7)*in_lo;
  u16* op = out + (long)z*out_slab;
  const int s0 = blockIdx.x*64, c0 = blockIdx.y*64;
  const int rl = t>>4, cc = (t&15)*4;
#pragma unroll
  for (int rr=0; rr<4; rr++){
    int row = rr*16 + rl;
    float v[4];
    ld4(ip + (long)(c0+row)*in_pitch + s0 + cc, v);
    tile[row][cc+0]=v[0]; tile[row][cc+1]=v[1]; tile[row][cc+2]=v[2]; tile[row][cc+3]=v[3];
  }
  __syncthreads();
#pragma unroll
  for (int wr=0; wr<4; wr++){
    int sl = wr*16 + rl;
    ushort4 s;
    s.x = f2bf(tile[cc+0][sl]); s.y = f2bf(tile[cc+1][sl]);
    s.z = f2bf(tile[cc+2][sl]); s.w = f2bf(tile[cc+3][sl]);
    *(ushort4*)(op + (long)(s0+sl)*192 + c0 + cc) = s;
  }
}

// ---- fused qkv GEMM v3 (NN, fp32 x read directly):
// A-fragments read straight from global (A is 221KB, L2-hot) -> no As LDS, no
// gl2lds, no 4-way As bank conflicts. LDS = B double-buffer only (18.4KB).
// Per k-step: issue next B tile->regs, load current A-frags, ds_read B-frags,
// 16 MFMA, pack+write next B, ONE light barrier. Bs pitch 36 halves
// (8B-aligned rows, conflict-free b64 reads, ~2-way writes).
__global__ __launch_bounds__(256,3) void gemm_qkv_kernel(
    const u16* __restrict__ A, const float* __restrict__ X, u16* __restrict__ C)
{
  __shared__ __align__(16) u16 Bs[2][128*36];
  const int t = threadIdx.x, w = t>>6, l = t&63;
  const int wrk = xcd_remap();
  const int mt = wrk % 5;
  const int rest = wrk / 5;
  const int nt = rest % 512, bz = rest / 512;
  const int m0 = mt*128, n0 = nt*128;
  const float* Xb = X + (long)bz*12582912L + n0;
  const int bq = t&31;        // lane column base (cols bq + 32c)
  const int kb = (t>>5)*4;    // k-row base (4 rows)
  // A-fragment pointers (k-offset folded; clamp rows for mt=4 tail)
  const u16* aptr[4];
#pragma unroll
  for (int i=0;i<4;i++){
    int row = m0 + (w>>1)*64 + i*16 + (l&15);
    if (row > 575) row = 575;
    aptr[i] = A + (long)row*192 + (l>>4)*8;
  }
  f32x4 acc[4][4];
#pragma unroll
  for (int i=0;i<4;i++)
#pragma unroll
    for (int j=0;j<4;j++) acc[i][j] = f32x4{0.f,0.f,0.f,0.f};

  // ---- prologue: stage B k0=0 into buffer 0
  {
    float xv[4][4];
#pragma unroll
    for (int i=0;i<4;i++){
      const float* xr = Xb + (long)(kb+i)*65536 + bq;
#pragma unroll
      for (int c=0;c<4;c++) xv[i][c] = xr[c*32];
    }
#pragma unroll
    for (int c=0;c<4;c++){
      u16* bw = Bs[0] + (bq + c*32)*36 + kb;
      *(u32*)(bw)     = pack2(xv[0][c], xv[1][c]);
      *(u32*)(bw + 2) = pack2(xv[2][c], xv[3][c]);
    }
  }
  __syncthreads();

  int cur = 0;
#pragma unroll
  for (int k0=0; k0<192; k0+=32){
    float nv[4][4];
    if (k0 < 160){
      // issue next-tile B loads first; latency hides under A-loads + MFMA
#pragma unroll
      for (int i=0;i<4;i++){
        const float* xr = Xb + (long)(k0+32+kb+i)*65536 + bq;
#pragma unroll
        for (int c=0;c<4;c++) nv[i][c] = xr[c*32];
      }
    }
    bf16x8 a[4], b[4];
#pragma unroll
    for (int i=0;i<4;i++) a[i] = *(const bf16x8*)(aptr[i] + k0);
    const u16* bp = Bs[cur] + ((w&1)*64 + (l&15))*36 + (l>>4)*8;
#pragma unroll
    for (int j=0;j<4;j++){
      uint2 p0 = *(const uint2*)(bp + j*576);
      uint2 p1 = *(const uint2*)(bp + j*576 + 4);
      u32x4 tv = {p0.x, p0.y, p1.x, p1.y};
      b[j] = __builtin_bit_cast(bf16x8, tv);
    }
#pragma unroll
    for (int i=0;i<4;i++)
#pragma unroll
      for (int j=0;j<4;j++) acc[i][j] = MFMA16(a[i], b[j], acc[i][j]);
    if (k0 < 160){
#pragma unroll
      for (int c=0;c<4;c++){
        u16* bw = Bs[cur^1] + (bq + c*32)*36 + kb;
        *(u32*)(bw)     = pack2(nv[0][c], nv[1][c]);
        *(u32*)(bw + 2) = pack2(nv[2][c], nv[3][c]);
      }
      __syncthreads();   // Bs[cur^1] visible; prev reads of it fenced by prior barrier
      cur ^= 1;
    }
  }
  const int mw = m0 + (w>>1)*64, nw = n0 + (w&1)*64;
  u16* Cb = C + (long)bz*37748736L;
#pragma unroll
  for (int i=0;i<4;i++){
#pragma unroll
    for (int r=0;r<4;r++){
      int row = mw + i*16 + (l>>4)*4 + r;
      if (row < 576){
        u16* cp = Cb + (long)row*65536 + nw + (l&15);
#pragma unroll
        for (int j=0;j<4;j++) stc(cp + j*16, acc[i][j][r]);
      }
    }
  }
}

// ---- NT MFMA GEMM (proj): C[m][n] = sum_k A[m][k]*B[n][k]; K=192
template<typename TC>
__global__ __launch_bounds__(256) void gemm_nt_kernel(
    const u16* __restrict__ A, const u16* __restrict__ B, TC* __restrict__ C,
    int M, long sB, long sC)
{
  __shared__ __align__(16) u16 As[128*32];
  __shared__ __align__(16) u16 Bs[128*32];
  const int t = threadIdx.x, w = t>>6, l = t&63;
  const int wrk = xcd_remap();
  const int mt = wrk % gridDim.x;
  const int rest = wrk / gridDim.x;
  const int nt = rest % gridDim.y, bz = rest / gridDim.y;
  const int m0 = mt*128, n0 = nt*128;
  const u16* Bb = B + (long)bz*sB + (long)n0*192;
  const int rq = t>>2, qq = (t&3)*8;
  int ar0 = m0 + rq;      if (ar0 >= M) ar0 = M-1;
  int ar1 = m0 + 64 + rq; if (ar1 >= M) ar1 = M-1;
  f32x4 acc[4][4];
#pragma unroll
  for (int i=0;i<4;i++)
#pragma unroll
    for (int j=0;j<4;j++) acc[i][j] = f32x4{0.f,0.f,0.f,0.f};

  for (int k0=0; k0<192; k0+=32){
    __syncthreads();
    gl2lds(A + (long)ar0*192 + k0 + qq, As + t*8);
    gl2lds(A + (long)ar1*192 + k0 + qq, As + (256+t)*8);
    gl2lds(Bb + (long)rq*192 + k0 + qq, Bs + t*8);
    gl2lds(Bb + (long)(64+rq)*192 + k0 + qq, Bs + (256+t)*8);
    __syncthreads();
    const u16* ap = As + ((w>>1)*64 + (l&15))*32 + (l>>4)*8;
    const u16* bp = Bs + ((w&1)*64 + (l&15))*32 + (l>>4)*8;
    bf16x8 a[4], b[4];
#pragma unroll
    for (int i=0;i<4;i++){ a[i] = *(const bf16x8*)(ap + i*512); b[i] = *(const bf16x8*)(bp + i*512); }
#pragma unroll
    for (int i=0;i<4;i++)
#pragma unroll
      for (int j=0;j<4;j++) acc[i][j] = MFMA16(a[i], b[j], acc[i][j]);
  }
  const int mw = m0 + (w>>1)*64, nw = n0 + (w&1)*64;
  TC* Cb = C + (long)bz*sC;
#pragma unroll
  for (int i=0;i<4;i++){
#pragma unroll
    for (int r=0;r<4;r++){
      int row = mw + i*16 + (l>>4)*4 + r;
      if (row < M){
        TC* cp = Cb + (long)row*65536 + nw + (l&15);
#pragma unroll
        for (int j=0;j<4;j++) stc(cp + j*16, acc[i][j][r]);
      }
    }
  }
}

// ---- depthwise 3x3 + fused sum-of-squares, register-streaming.
// 32-lane row groups, 8 cols/lane (16B loads/stores). Wave = 32 output rows
// (2 groups x 16) = exactly one norms bucket. No LDS, no barriers, no atomics.
__global__ __launch_bounds__(256) void dwconv_kernel(
    const u16* __restrict__ in, const float* __restrict__ w9s,
    u16* __restrict__ out, float* __restrict__ norms)
{
  const int bo = blockIdx.x >> 1;   // channel slab (b*576 + o)
  const int half = blockIdx.x & 1;  // 128-row half
  const int o  = bo % 576;
  const int t = threadIdx.x, wv = t>>6, l = t&63;
  const int q = l&31;
  const int r0 = half*128 + wv*32 + (l>>5)*16;  // first output row, this group
  const u16* ip = in + (long)bo*65536L + q*8;
  u16* op = out + (long)bo*65536L + q*8;
  float w[9];
#pragma unroll
  for (int i=0;i<9;i++) w[i] = w9s[o*9+i];
  float ap[8], ac[8], an[8];
#pragma unroll
  for (int c=0;c<8;c++){ ap[c]=0.f; ac[c]=0.f; }
  float ss = 0.f;
#pragma unroll
  for (int it=0; it<18; ++it){
    const int g = r0 - 1 + it;    // input row
    float v[8];
    if (g>=0 && g<256){
      u16x8 u = *(const u16x8*)(ip + g*256);
#pragma unroll
      for (int c=0;c<8;c++) v[c] = bf2f(u[c]);
    } else {
#pragma unroll
      for (int c=0;c<8;c++) v[c]=0.f;
    }
    float slv = __shfl(v[7], (l+63)&63);
    float srv = __shfl(v[0], (l+1)&63);
    const float lf  = (q==0)  ? 0.f : slv;
    const float rgt = (q==31) ? 0.f : srv;
#pragma unroll
    for (int c=0;c<8;c++){
      const float le = (c==0) ? lf  : v[c-1];
      const float mi = v[c];
      const float ri = (c==7) ? rgt : v[c+1];
      ap[c] = fmaf(w[6],le, fmaf(w[7],mi, fmaf(w[8],ri, ap[c])));
      ac[c] = fmaf(w[3],le, fmaf(w[4],mi, fmaf(w[5],ri, ac[c])));
      an[c] = fmaf(w[0],le, fmaf(w[1],mi, w[2]*ri));
    }
    if (it >= 2){
      u16x8 s;
#pragma unroll
      for (int c=0;c<8;c++){ s[c] = f2bf(ap[c]); ss = fmaf(ap[c],ap[c],ss); }
      *(u16x8*)(op + (g-1)*256) = s;
    }
#pragma unroll
    for (int c=0;c<8;c++){ ap[c]=ac[c]; ac[c]=an[c]; }
  }
#pragma unroll
  for (int off=32; off>=1; off>>=1) ss += __shfl_xor(ss, off);
  if (o < 384 && l == 0)
    norms[bo*8 + half*4 + wv] = ss;   // single writer per bucket
}

// ---- QK^T MFMA, K-split partials ----
__global__ __launch_bounds__(256) void gemm_qk_kernel(
    const u16* __restrict__ conv, float* __restrict__ part)
{
  __shared__ __align__(16) u16 As[64*64];
  __shared__ __align__(16) u16 Bs[64*64];
  const int t = threadIdx.x, w = t>>6, l = t&63;
  const int wrk = xcd_remap();
  const int mt = wrk % 3;
  const int rest = wrk / 3;
  const int nt = rest % 3, z = rest / 3;
  const int bh = z>>3, sl = z&7;
  const int b = bh>>3, h = bh&7;
  const u16* Q  = conv + (long)b*37748736L + (long)h*1572864L;
  const u16* Kp = Q + 12582912L;
  const int m0 = mt*64, n0 = nt*64;
  const int rq = t>>3, qq = (t&7)*8;
  const long qo0 = (long)(m0+rq)*8192 + qq;
  const long qo1 = (long)(m0+32+rq)*8192 + qq;
  const long ko0 = (long)(n0+rq)*8192 + qq;
  const long ko1 = (long)(n0+32+rq)*8192 + qq;
  f32x4 acc[2][2];
#pragma unroll
  for (int i=0;i<2;i++)
#pragma unroll
    for (int j=0;j<2;j++) acc[i][j] = f32x4{0.f,0.f,0.f,0.f};
  const int kbeg = sl*1024;
  for (int k0=kbeg; k0<kbeg+1024; k0+=64){
    __syncthreads();
    gl2lds(Q  + qo0 + k0, As + t*8);
    gl2lds(Q  + qo1 + k0, As + (256+t)*8);
    gl2lds(Kp + ko0 + k0, Bs + t*8);
    gl2lds(Kp + ko1 + k0, Bs + (256+t)*8);
    __syncthreads();
    const u16* ap = As + ((w>>1)*32 + (l&15))*64 + (l>>4)*8;
    const u16* bp = Bs + ((w&1)*32 + (l&15))*64 + (l>>4)*8;
#pragma unroll
    for (int ks=0; ks<2; ks++){
      bf16x8 a0 = *(const bf16x8*)(ap + ks*32);
      bf16x8 a1 = *(const bf16x8*)(ap + 1024 + ks*32);
      bf16x8 b0 = *(const bf16x8*)(bp + ks*32);
      bf16x8 b1 = *(const bf16x8*)(bp + 1024 + ks*32);
      acc[0][0]=MFMA16(a0,b0,acc[0][0]); acc[0][1]=MFMA16(a0,b1,acc[0][1]);
      acc[1][0]=MFMA16(a1,b0,acc[1][0]); acc[1][1]=MFMA16(a1,b1,acc[1][1]);
    }
  }
  float* P = part + (long)z*36864L;
  const int mw = m0 + (w>>1)*32, nw = n0 + (w&1)*32;
#pragma unroll
  for (int i=0;i<2;i++)
#pragma unroll
    for (int j=0;j<2;j++)
#pragma unroll
      for (int r=0;r<4;r++)
        P[(long)(mw + i*16 + (l>>4)*4 + r)*192 + nw + j*16 + (l&15)] = acc[i][j][r];
}

// ---- reduce partials + l2norm scales + temperature + softmax -> attn bf16 ----
// 256 threads = 4 independent waves, one attn row each.
__global__ __launch_bounds__(256) void softmax_kernel(
    const float* __restrict__ part, const float* __restrict__ temp,
    const float* __restrict__ norms, u16* __restrict__ attn)
{
  const int t = threadIdx.x, wv = t>>6, l = t&63;
  const int rg = blockIdx.x*4 + wv;
  const int bh = rg/192, r = rg - bh*192;
  const int b = bh>>3, h = bh&7;
  const float tp = temp[h];
  const float sq = norms[(b*576 + 24*h + (r>>3))*8 + (r&7)];
  const float invq = 1.f/fmaxf(sqrtf(sq), 1e-12f);
  const float* P = part + (long)bh*8L*36864L + (long)r*192;
  float lv[3];
#pragma unroll
  for (int j=0;j<3;j++){
    int col = l + j*64;
    float s = 0.f;
#pragma unroll
    for (int ks=0; ks<8; ks++) s += P[(long)ks*36864L + col];
    float sk = norms[(b*576 + 192 + 24*h + (col>>3))*8 + (col&7)];
    float invk = 1.f/fmaxf(sqrtf(sk), 1e-12f);
    lv[j] = s*invq*invk*tp;
  }
  float mx = fmaxf(lv[0], fmaxf(lv[1], lv[2]));
#pragma unroll
  for (int o=32;o>=1;o>>=1) mx = fmaxf(mx, __shfl_xor(mx, o));
  float e[3], sum = 0.f;
#pragma unroll
  for (int j=0;j<3;j++){ e[j] = expf(lv[j]-mx); sum += e[j]; }
#pragma unroll
  for (int o=32;o>=1;o>>=1) sum += __shfl_xor(sum, o);
  const float inv = 1.f/sum;
  u16* ap = attn + (long)bh*36864L + (long)r*192;
#pragma unroll
  for (int j=0;j<3;j++) ap[l + j*64] = f2bf(e[j]*inv);
}

// ---- attn@V with LDS-bounce epilogue -> out_sc[s][C] ----
__global__ __launch_bounds__(256) void gemm_av_kernel(
    const u16* __restrict__ VT, const u16* __restrict__ attn, u16* __restrict__ out_sc)
{
  __shared__ __align__(16) char smem[69632];
  u16* As = (u16*)smem;
  u16* Bs = (u16*)(smem + 8192);
  const int t = threadIdx.x, w = t>>6, l = t&63;
  const int wrk = xcd_remap();
  const int mt = wrk % 64;
  const int rest = wrk / 64;
  const int nt = rest % 2, bh = rest / 2;
  const int b = bh>>3, h = bh&7;
  const u16* Av = VT + (long)bh*1572864L;
  const u16* Bt = attn + (long)bh*36864L;
  const int m0 = mt*128, n0 = nt*128;
  const int rq = t>>2, qq = (t&3)*8;
  int br0 = n0 + rq;      if (br0 > 191) br0 = 191;
  int br1 = n0 + 64 + rq; if (br1 > 191) br1 = 191;
  f32x4 acc[4][4];
#pragma unroll
  for (int i=0;i<4;i++)
#pragma unroll
    for (int j=0;j<4;j++) acc[i][j] = f32x4{0.f,0.f,0.f,0.f};
  for (int k0=0; k0<192; k0+=32){
    __syncthreads();
    gl2lds(Av + (long)(m0+rq)*192 + k0 + qq, As + t*8);
    gl2lds(Av + (long)(m0+64+rq)*192 + k0 + qq, As + (256+t)*8);
    gl2lds(Bt + (long)br0*192 + k0 + qq, Bs + t*8);
    gl2lds(Bt + (long)br1*192 + k0 + qq, Bs + (256+t)*8);
    __syncthreads();
    const u16* ap = As + ((w>>1)*64 + (l&15))*32 + (l>>4)*8;
    const u16* bp = Bs + ((w&1)*64 + (l&15))*32 + (l>>4)*8;
    bf16x8 a[4], bb[4];
#pragma unroll
    for (int i=0;i<4;i++){ a[i] = *(const bf16x8*)(ap + i*512); bb[i] = *(const bf16x8*)(bp + i*512); }
#pragma unroll
    for (int i=0;i<4;i++)
#pragma unroll
      for (int j=0;j<4;j++) acc[i][j] = MFMA16(a[i], bb[j], acc[i][j]);
  }
  __syncthreads();
  float* wb = (float*)smem + w*4352;
#pragma unroll
  for (int i=0;i<4;i++)
#pragma unroll
    for (int j=0;j<4;j++)
#pragma unroll
      for (int r=0;r<4;r++)
        wb[(i*16 + (l>>4)*4 + r)*68 + j*16 + (l&15)] = acc[i][j][r];
  __syncthreads();
  const int c0w = nt*128 + (w&1)*64;
  if (c0w < 192){
    const int cb = 24*h + (c0w>>3);
    const int mw = m0 + (w>>1)*64;
    u16* ob = out_sc + (long)b*12582912L + cb;
    const int nl0 = l>>3, sb = l&7;
#pragma unroll
    for (int ri=0; ri<8; ri++){
      int nl = ri*8 + nl0;
      const float* src = wb + nl*68 + sb;
      u32 d0 = (u32)f2bf(src[0])  | ((u32)f2bf(src[8])  << 16);
      u32 d1 = (u32)f2bf(src[16]) | ((u32)f2bf(src[24]) << 16);
      u32 d2 = (u32)f2bf(src[32]) | ((u32)f2bf(src[40]) << 16);
      u32 d3 = (u32)f2bf(src[48]) | ((u32)f2bf(src[56]) << 16);
      *(uint4*)(ob + ((long)sb*8192 + mw + nl)*192) = make_uint4(d0,d1,d2,d3);
    }
  }
}

extern "C" void kernel_launch(void* const* d_in, const int* in_sizes, int n_in,
                              void* d_out, int out_size, void* d_ws, size_t ws_size,
                              hipStream_t stream)
{
  const float* x      = (const float*)d_in[0];
  const float* qkv_w  = (const float*)d_in[1];
  const float* dw_w   = (const float*)d_in[2];
  const float* proj_w = (const float*)d_in[3];
  const float* temp   = (const float*)d_in[4];
  float* out = (float*)d_out;

  // workspace layout. qkv_raw live in [150994944, 301989888) until dwconv done;
  // VT/out_sc/part/attn reuse that range after. wq/wp/norms live across the qkv
  // GEMM -> placed PAST 301989888 (aliasing here was the round-2/3 NaN bug).
  char* ws = (char*)d_ws;
  u16*   conv    = (u16*)(ws + 0);
  u16*   qkv_raw = (u16*)(ws + 150994944);
  u16*   VT      = (u16*)(ws + 150994944);
  u16*   out_sc  = (u16*)(ws + 201326592);
  float* part    = (float*)(ws + 251658240);
  u16*   attn    = (u16*)(ws + 270532608);
  u16*   wq_bf   = (u16*)(ws + 301989888);
  u16*   wp_bf   = (u16*)(ws + 302211072);
  float* norms   = (float*)(ws + 302284800);

  prep_kernel<<<dim3(612), 256, 0, stream>>>(qkv_w, proj_w, wq_bf, wp_bf, norms);

  // qkv_raw = qkv_w @ x  -- fused NN GEMM, reads x [c][s] fp32 directly
  gemm_qkv_kernel<<<dim3(5, 512, 2), 256, 0, stream>>>(wq_bf, x, qkv_raw);

  // depthwise 3x3 + q/k sum-of-squares (register-streaming, 8 cols/lane)
  dwconv_kernel<<<dim3(1152*2), 256, 0, stream>>>(qkv_raw, dw_w, conv, norms);

  // VT[bh][n][d] = Vslab[d][n]
  transpose_kernel<<<dim3(128, 3, 16), 256, 0, stream>>>(
      conv + 25165824L, VT, 37748736L, 1572864L, 1572864L, 8192);

  // raw QK^T partials
  gemm_qk_kernel<<<dim3(3, 3, 128), 256, 0, stream>>>(conv, part);

  // reduce + normalize + temperature + softmax -> attn (bf16)
  softmax_kernel<<<dim3(768), 256, 0, stream>>>(part, temp, norms, attn);

  // attn @ V -> out_sc [b][s][C]
  gemm_av_kernel<<<dim3(64, 2, 16), 256, 0, stream>>>(VT, attn, out_sc);

  // out = proj_w @ attn_out (NT vs out_sc), M=192, fp32 out
  gemm_nt_kernel<float><<<dim3(2, 512, 2), 256, 0, stream>>>(
      wp_bf, out_sc, out, 192, 12582912L, 12582912L);
}

// Round 8
// 460.246 us; speedup vs baseline: 1.0401x; 1.0401x over previous
//
#include <hip/hip_runtime.h>
#include <math.h>

typedef unsigned short u16;
typedef unsigned int   u32;
typedef short bf16x8 __attribute__((ext_vector_type(8)));
typedef float f32x4  __attribute__((ext_vector_type(4)));
typedef u16 u16x8 __attribute__((ext_vector_type(8)));

#define MFMA16(a,b,c) __builtin_amdgcn_mfma_f32_16x16x32_bf16((a),(b),(c),0,0,0)

__device__ __forceinline__ float bf2f(u16 h){ u32 u=((u32)h)<<16; return __uint_as_float(u); }
__device__ __forceinline__ u16 f2bf(float f){ u32 u=__float_as_uint(f); return (u16)((u+0x7fffu+((u>>16)&1u))>>16); }

// async global->LDS, 16B/lane. LDS dest is wave-uniform base + lane*16 (m97 pattern).
__device__ __forceinline__ void gl2lds(const u16* g, u16* l){
  __builtin_amdgcn_global_load_lds((const __attribute__((address_space(1))) u32*)g,
                                   (__attribute__((address_space(3))) u32*)l, 16, 0, 0);
}
__device__ __forceinline__ void stc(u16* p, float v){ *p = f2bf(v); }
__device__ __forceinline__ void stc(float* p, float v){ *p = v; }
__device__ __forceinline__ void ld4(const float* p, float* v){ float4 x=*(const float4*)p; v[0]=x.x;v[1]=x.y;v[2]=x.z;v[3]=x.w; }
__device__ __forceinline__ void ld4(const u16* p, float* v){ ushort4 x=*(const ushort4*)p; v[0]=bf2f(x.x);v[1]=bf2f(x.y);v[2]=bf2f(x.z);v[3]=bf2f(x.w); }

// XCD-aware bijective block remap (T1, m204 form). Requires nwg % 8 == 0.
__device__ __forceinline__ int xcd_remap(){
  int gx = gridDim.x, gy = gridDim.y;
  int lin = blockIdx.x + gx*(blockIdx.y + gy*blockIdx.z);
  int nwg = gx*gy*gridDim.z;
  if (nwg & 7) return lin;
  int q = nwg >> 3;
  return (lin & 7)*q + (lin >> 3);
}

// ---- prep: cvt weights to bf16 + zero norms (one dispatch) ----
__global__ void prep_kernel(const float* __restrict__ qkv_w, const float* __restrict__ proj_w,
                            u16* __restrict__ wq, u16* __restrict__ wp, float* __restrict__ norms){
  int i = blockIdx.x*256 + threadIdx.x;
  if (i < 110592) wq[i] = f2bf(qkv_w[i]);
  else if (i < 147456) wp[i-110592] = f2bf(proj_w[i-110592]);
  else if (i < 156672) norms[i-147456] = 0.f;
}

// ---- tiled transpose: in [z][192][in_pitch] (TIN) -> out [z][cols][192] bf16 ----
template<typename TIN>
__global__ __launch_bounds__(256) void transpose_kernel(
    const TIN* __restrict__ in, u16* __restrict__ out,
    long in_hi, long in_lo, long out_slab, int in_pitch)
{
  __shared__ float tile[64][65];
  const int t = threadIdx.x;
  const int z = blockIdx.z;
  const TIN* ip = in + (long)(z>>3)*in_hi + (long)(z&7)*in_lo;
  u16* op = out + (long)z*out_slab;
  const int s0 = blockIdx.x*64, c0 = blockIdx.y*64;
  const int rl = t>>4, cc = (t&15)*4;
#pragma unroll
  for (int rr=0; rr<4; rr++){
    int row = rr*16 + rl;
    float v[4];
    ld4(ip + (long)(c0+row)*in_pitch + s0 + cc, v);
    tile[row][cc+0]=v[0]; tile[row][cc+1]=v[1]; tile[row][cc+2]=v[2]; tile[row][cc+3]=v[3];
  }
  __syncthreads();
#pragma unroll
  for (int wr=0; wr<4; wr++){
    int sl = wr*16 + rl;
    ushort4 s;
    s.x = f2bf(tile[cc+0][sl]); s.y = f2bf(tile[cc+1][sl]);
    s.z = f2bf(tile[cc+2][sl]); s.w = f2bf(tile[cc+3][sl]);
    *(ushort4*)(op + (long)(s0+sl)*192 + c0 + cc) = s;
  }
}

// ---- NT MFMA GEMM: C[m][n] = sum_k A[m][k]*B[n][k]; K=192, lda=ldb=192, ldc=65536
template<typename TC>
__global__ __launch_bounds__(256) void gemm_nt_kernel(
    const u16* __restrict__ A, const u16* __restrict__ B, TC* __restrict__ C,
    int M, long sB, long sC)
{
  __shared__ __align__(16) u16 As[128*32];
  __shared__ __align__(16) u16 Bs[128*32];
  const int t = threadIdx.x, w = t>>6, l = t&63;
  const int wrk = xcd_remap();
  const int mt = wrk % gridDim.x;
  const int rest = wrk / gridDim.x;
  const int nt = rest % gridDim.y, bz = rest / gridDim.y;
  const int m0 = mt*128, n0 = nt*128;
  const u16* Bb = B + (long)bz*sB + (long)n0*192;
  const int rq = t>>2, qq = (t&3)*8;
  int ar0 = m0 + rq;      if (ar0 >= M) ar0 = M-1;
  int ar1 = m0 + 64 + rq; if (ar1 >= M) ar1 = M-1;
  f32x4 acc[4][4];
#pragma unroll
  for (int i=0;i<4;i++)
#pragma unroll
    for (int j=0;j<4;j++) acc[i][j] = f32x4{0.f,0.f,0.f,0.f};

  for (int k0=0; k0<192; k0+=32){
    __syncthreads();
    gl2lds(A + (long)ar0*192 + k0 + qq, As + t*8);
    gl2lds(A + (long)ar1*192 + k0 + qq, As + (256+t)*8);
    gl2lds(Bb + (long)rq*192 + k0 + qq, Bs + t*8);
    gl2lds(Bb + (long)(64+rq)*192 + k0 + qq, Bs + (256+t)*8);
    __syncthreads();
    const u16* ap = As + ((w>>1)*64 + (l&15))*32 + (l>>4)*8;
    const u16* bp = Bs + ((w&1)*64 + (l&15))*32 + (l>>4)*8;
    bf16x8 a[4], b[4];
#pragma unroll
    for (int i=0;i<4;i++){ a[i] = *(const bf16x8*)(ap + i*512); b[i] = *(const bf16x8*)(bp + i*512); }
#pragma unroll
    for (int i=0;i<4;i++)
#pragma unroll
      for (int j=0;j<4;j++) acc[i][j] = MFMA16(a[i], b[j], acc[i][j]);
  }
  const int mw = m0 + (w>>1)*64, nw = n0 + (w&1)*64;
  TC* Cb = C + (long)bz*sC;
#pragma unroll
  for (int i=0;i<4;i++){
#pragma unroll
    for (int r=0;r<4;r++){
      int row = mw + i*16 + (l>>4)*4 + r;
      if (row < M){
        TC* cp = Cb + (long)row*65536 + nw + (l&15);
#pragma unroll
        for (int j=0;j<4;j++) stc(cp + j*16, acc[i][j][r]);
      }
    }
  }
}

// ---- depthwise 3x3 + fused sum-of-squares, register-streaming.
// 32-lane row groups, 8 cols/lane (16B loads/stores). Wave = 32 output rows
// (2 groups x 16) = exactly one norms bucket. No LDS, no barriers, no atomics.
__global__ __launch_bounds__(256) void dwconv_kernel(
    const u16* __restrict__ in, const float* __restrict__ w9s,
    u16* __restrict__ out, float* __restrict__ norms)
{
  const int bo = blockIdx.x >> 1;   // channel slab (b*576 + o)
  const int half = blockIdx.x & 1;  // 128-row half
  const int o  = bo % 576;
  const int t = threadIdx.x, wv = t>>6, l = t&63;
  const int q = l&31;
  const int r0 = half*128 + wv*32 + (l>>5)*16;  // first output row, this group
  const u16* ip = in + (long)bo*65536L + q*8;
  u16* op = out + (long)bo*65536L + q*8;
  float w[9];
#pragma unroll
  for (int i=0;i<9;i++) w[i] = w9s[o*9+i];
  float ap[8], ac[8], an[8];
#pragma unroll
  for (int c=0;c<8;c++){ ap[c]=0.f; ac[c]=0.f; }
  float ss = 0.f;
#pragma unroll
  for (int it=0; it<18; ++it){
    const int g = r0 - 1 + it;    // input row
    float v[8];
    if (g>=0 && g<256){
      u16x8 u = *(const u16x8*)(ip + g*256);
#pragma unroll
      for (int c=0;c<8;c++) v[c] = bf2f(u[c]);
    } else {
#pragma unroll
      for (int c=0;c<8;c++) v[c]=0.f;
    }
    float slv = __shfl(v[7], (l+63)&63);
    float srv = __shfl(v[0], (l+1)&63);
    const float lf  = (q==0)  ? 0.f : slv;
    const float rgt = (q==31) ? 0.f : srv;
#pragma unroll
    for (int c=0;c<8;c++){
      const float le = (c==0) ? lf  : v[c-1];
      const float mi = v[c];
      const float ri = (c==7) ? rgt : v[c+1];
      ap[c] = fmaf(w[6],le, fmaf(w[7],mi, fmaf(w[8],ri, ap[c])));
      ac[c] = fmaf(w[3],le, fmaf(w[4],mi, fmaf(w[5],ri, ac[c])));
      an[c] = fmaf(w[0],le, fmaf(w[1],mi, w[2]*ri));
    }
    if (it >= 2){
      u16x8 s;
#pragma unroll
      for (int c=0;c<8;c++){ s[c] = f2bf(ap[c]); ss = fmaf(ap[c],ap[c],ss); }
      *(u16x8*)(op + (g-1)*256) = s;
    }
#pragma unroll
    for (int c=0;c<8;c++){ ap[c]=ac[c]; ac[c]=an[c]; }
  }
#pragma unroll
  for (int off=32; off>=1; off>>=1) ss += __shfl_xor(ss, off);
  if (o < 384 && l == 0)
    norms[bo*8 + half*4 + wv] = ss;   // single writer per bucket
}

// ---- QK^T MFMA, K-split partials ----
__global__ __launch_bounds__(256) void gemm_qk_kernel(
    const u16* __restrict__ conv, float* __restrict__ part)
{
  __shared__ __align__(16) u16 As[64*64];
  __shared__ __align__(16) u16 Bs[64*64];
  const int t = threadIdx.x, w = t>>6, l = t&63;
  const int wrk = xcd_remap();
  const int mt = wrk % 3;
  const int rest = wrk / 3;
  const int nt = rest % 3, z = rest / 3;
  const int bh = z>>3, sl = z&7;
  const int b = bh>>3, h = bh&7;
  const u16* Q  = conv + (long)b*37748736L + (long)h*1572864L;
  const u16* Kp = Q + 12582912L;
  const int m0 = mt*64, n0 = nt*64;
  const int rq = t>>3, qq = (t&7)*8;
  const long qo0 = (long)(m0+rq)*8192 + qq;
  const long qo1 = (long)(m0+32+rq)*8192 + qq;
  const long ko0 = (long)(n0+rq)*8192 + qq;
  const long ko1 = (long)(n0+32+rq)*8192 + qq;
  f32x4 acc[2][2];
#pragma unroll
  for (int i=0;i<2;i++)
#pragma unroll
    for (int j=0;j<2;j++) acc[i][j] = f32x4{0.f,0.f,0.f,0.f};
  const int kbeg = sl*1024;
  for (int k0=kbeg; k0<kbeg+1024; k0+=64){
    __syncthreads();
    gl2lds(Q  + qo0 + k0, As + t*8);
    gl2lds(Q  + qo1 + k0, As + (256+t)*8);
    gl2lds(Kp + ko0 + k0, Bs + t*8);
    gl2lds(Kp + ko1 + k0, Bs + (256+t)*8);
    __syncthreads();
    const u16* ap = As + ((w>>1)*32 + (l&15))*64 + (l>>4)*8;
    const u16* bp = Bs + ((w&1)*32 + (l&15))*64 + (l>>4)*8;
#pragma unroll
    for (int ks=0; ks<2; ks++){
      bf16x8 a0 = *(const bf16x8*)(ap + ks*32);
      bf16x8 a1 = *(const bf16x8*)(ap + 1024 + ks*32);
      bf16x8 b0 = *(const bf16x8*)(bp + ks*32);
      bf16x8 b1 = *(const bf16x8*)(bp + 1024 + ks*32);
      acc[0][0]=MFMA16(a0,b0,acc[0][0]); acc[0][1]=MFMA16(a0,b1,acc[0][1]);
      acc[1][0]=MFMA16(a1,b0,acc[1][0]); acc[1][1]=MFMA16(a1,b1,acc[1][1]);
    }
  }
  float* P = part + (long)z*36864L;
  const int mw = m0 + (w>>1)*32, nw = n0 + (w&1)*32;
#pragma unroll
  for (int i=0;i<2;i++)
#pragma unroll
    for (int j=0;j<2;j++)
#pragma unroll
      for (int r=0;r<4;r++)
        P[(long)(mw + i*16 + (l>>4)*4 + r)*192 + nw + j*16 + (l&15)] = acc[i][j][r];
}

// ---- reduce partials + l2norm scales + temperature + softmax -> attn bf16 ----
// 256 threads = 4 independent waves, one attn row each.
__global__ __launch_bounds__(256) void softmax_kernel(
    const float* __restrict__ part, const float* __restrict__ temp,
    const float* __restrict__ norms, u16* __restrict__ attn)
{
  const int t = threadIdx.x, wv = t>>6, l = t&63;
  const int rg = blockIdx.x*4 + wv;
  const int bh = rg/192, r = rg - bh*192;
  const int b = bh>>3, h = bh&7;
  const float tp = temp[h];
  const float sq = norms[(b*576 + 24*h + (r>>3))*8 + (r&7)];
  const float invq = 1.f/fmaxf(sqrtf(sq), 1e-12f);
  const float* P = part + (long)bh*8L*36864L + (long)r*192;
  float lv[3];
#pragma unroll
  for (int j=0;j<3;j++){
    int col = l + j*64;
    float s = 0.f;
#pragma unroll
    for (int ks=0; ks<8; ks++) s += P[(long)ks*36864L + col];
    float sk = norms[(b*576 + 192 + 24*h + (col>>3))*8 + (col&7)];
    float invk = 1.f/fmaxf(sqrtf(sk), 1e-12f);
    lv[j] = s*invq*invk*tp;
  }
  float mx = fmaxf(lv[0], fmaxf(lv[1], lv[2]));
#pragma unroll
  for (int o=32;o>=1;o>>=1) mx = fmaxf(mx, __shfl_xor(mx, o));
  float e[3], sum = 0.f;
#pragma unroll
  for (int j=0;j<3;j++){ e[j] = expf(lv[j]-mx); sum += e[j]; }
#pragma unroll
  for (int o=32;o>=1;o>>=1) sum += __shfl_xor(sum, o);
  const float inv = 1.f/sum;
  u16* ap = attn + (long)bh*36864L + (long)r*192;
#pragma unroll
  for (int j=0;j<3;j++) ap[l + j*64] = f2bf(e[j]*inv);
}

// ---- attn@V with LDS-bounce epilogue -> out_sc[s][C] ----
__global__ __launch_bounds__(256) void gemm_av_kernel(
    const u16* __restrict__ VT, const u16* __restrict__ attn, u16* __restrict__ out_sc)
{
  __shared__ __align__(16) char smem[69632];
  u16* As = (u16*)smem;
  u16* Bs = (u16*)(smem + 8192);
  const int t = threadIdx.x, w = t>>6, l = t&63;
  const int wrk = xcd_remap();
  const int mt = wrk % 64;
  const int rest = wrk / 64;
  const int nt = rest % 2, bh = rest / 2;
  const int b = bh>>3, h = bh&7;
  const u16* Av = VT + (long)bh*1572864L;
  const u16* Bt = attn + (long)bh*36864L;
  const int m0 = mt*128, n0 = nt*128;
  const int rq = t>>2, qq = (t&3)*8;
  int br0 = n0 + rq;      if (br0 > 191) br0 = 191;
  int br1 = n0 + 64 + rq; if (br1 > 191) br1 = 191;
  f32x4 acc[4][4];
#pragma unroll
  for (int i=0;i<4;i++)
#pragma unroll
    for (int j=0;j<4;j++) acc[i][j] = f32x4{0.f,0.f,0.f,0.f};
  for (int k0=0; k0<192; k0+=32){
    __syncthreads();
    gl2lds(Av + (long)(m0+rq)*192 + k0 + qq, As + t*8);
    gl2lds(Av + (long)(m0+64+rq)*192 + k0 + qq, As + (256+t)*8);
    gl2lds(Bt + (long)br0*192 + k0 + qq, Bs + t*8);
    gl2lds(Bt + (long)br1*192 + k0 + qq, Bs + (256+t)*8);
    __syncthreads();
    const u16* ap = As + ((w>>1)*64 + (l&15))*32 + (l>>4)*8;
    const u16* bp = Bs + ((w&1)*64 + (l&15))*32 + (l>>4)*8;
    bf16x8 a[4], bb[4];
#pragma unroll
    for (int i=0;i<4;i++){ a[i] = *(const bf16x8*)(ap + i*512); bb[i] = *(const bf16x8*)(bp + i*512); }
#pragma unroll
    for (int i=0;i<4;i++)
#pragma unroll
      for (int j=0;j<4;j++) acc[i][j] = MFMA16(a[i], bb[j], acc[i][j]);
  }
  __syncthreads();
  float* wb = (float*)smem + w*4352;
#pragma unroll
  for (int i=0;i<4;i++)
#pragma unroll
    for (int j=0;j<4;j++)
#pragma unroll
      for (int r=0;r<4;r++)
        wb[(i*16 + (l>>4)*4 + r)*68 + j*16 + (l&15)] = acc[i][j][r];
  __syncthreads();
  const int c0w = nt*128 + (w&1)*64;
  if (c0w < 192){
    const int cb = 24*h + (c0w>>3);
    const int mw = m0 + (w>>1)*64;
    u16* ob = out_sc + (long)b*12582912L + cb;
    const int nl0 = l>>3, sb = l&7;
#pragma unroll
    for (int ri=0; ri<8; ri++){
      int nl = ri*8 + nl0;
      const float* src = wb + nl*68 + sb;
      u32 d0 = (u32)f2bf(src[0])  | ((u32)f2bf(src[8])  << 16);
      u32 d1 = (u32)f2bf(src[16]) | ((u32)f2bf(src[24]) << 16);
      u32 d2 = (u32)f2bf(src[32]) | ((u32)f2bf(src[40]) << 16);
      u32 d3 = (u32)f2bf(src[48]) | ((u32)f2bf(src[56]) << 16);
      *(uint4*)(ob + ((long)sb*8192 + mw + nl)*192) = make_uint4(d0,d1,d2,d3);
    }
  }
}

extern "C" void kernel_launch(void* const* d_in, const int* in_sizes, int n_in,
                              void* d_out, int out_size, void* d_ws, size_t ws_size,
                              hipStream_t stream)
{
  const float* x      = (const float*)d_in[0];
  const float* qkv_w  = (const float*)d_in[1];
  const float* dw_w   = (const float*)d_in[2];
  const float* proj_w = (const float*)d_in[3];
  const float* temp   = (const float*)d_in[4];
  float* out = (float*)d_out;

  // workspace layout. qkv_raw live in [150994944, 301989888) until dwconv done;
  // VT/out_sc/part/attn reuse that range after. wq/wp/norms live across the qkv
  // GEMM -> placed PAST 301989888 (aliasing here was the round-2/3 NaN bug).
  char* ws = (char*)d_ws;
  u16*   xT      = (u16*)(ws + 0);
  u16*   conv    = (u16*)(ws + 0);
  u16*   qkv_raw = (u16*)(ws + 150994944);
  u16*   VT      = (u16*)(ws + 150994944);
  u16*   out_sc  = (u16*)(ws + 201326592);
  float* part    = (float*)(ws + 251658240);
  u16*   attn    = (u16*)(ws + 270532608);
  u16*   wq_bf   = (u16*)(ws + 301989888);
  u16*   wp_bf   = (u16*)(ws + 302211072);
  float* norms   = (float*)(ws + 302284800);

  prep_kernel<<<dim3(612), 256, 0, stream>>>(qkv_w, proj_w, wq_bf, wp_bf, norms);

  // xT[b][s][c] = x[b][c][s]
  transpose_kernel<float><<<dim3(1024, 3, 2), 256, 0, stream>>>(
      x, xT, 0L, 12582912L, 12582912L, 65536);

  // qkv_raw = qkv_w @ x  (NT vs xT), M=576
  gemm_nt_kernel<u16><<<dim3(5, 512, 2), 256, 0, stream>>>(
      wq_bf, xT, qkv_raw, 576, 12582912L, 37748736L);

  // depthwise 3x3 + q/k sum-of-squares (register-streaming, 8 cols/lane)
  dwconv_kernel<<<dim3(1152*2), 256, 0, stream>>>(qkv_raw, dw_w, conv, norms);

  // VT[bh][n][d] = Vslab[d][n]
  transpose_kernel<u16><<<dim3(128, 3, 16), 256, 0, stream>>>(
      conv + 25165824L, VT, 37748736L, 1572864L, 1572864L, 8192);

  // raw QK^T partials
  gemm_qk_kernel<<<dim3(3, 3, 128), 256, 0, stream>>>(conv, part);

  // reduce + normalize + temperature + softmax -> attn (bf16)
  softmax_kernel<<<dim3(768), 256, 0, stream>>>(part, temp, norms, attn);

  // attn @ V -> out_sc [b][s][C]
  gemm_av_kernel<<<dim3(64, 2, 16), 256, 0, stream>>>(VT, attn, out_sc);

  // out = proj_w @ attn_out (NT vs out_sc), M=192, fp32 out
  gemm_nt_kernel<float><<<dim3(2, 512, 2), 256, 0, stream>>>(
      wp_bf, out_sc, out, 192, 12582912L, 12582912L);
}

// Round 9
// 451.496 us; speedup vs baseline: 1.0603x; 1.0194x over previous
//
#include <hip/hip_runtime.h>
#include <math.h>

typedef unsigned short u16;
typedef unsigned int   u32;
typedef short bf16x8 __attribute__((ext_vector_type(8)));
typedef float f32x4  __attribute__((ext_vector_type(4)));
typedef u16 u16x8 __attribute__((ext_vector_type(8)));

#define MFMA16(a,b,c) __builtin_amdgcn_mfma_f32_16x16x32_bf16((a),(b),(c),0,0,0)

__device__ __forceinline__ float bf2f(u16 h){ u32 u=((u32)h)<<16; return __uint_as_float(u); }
__device__ __forceinline__ u16 f2bf(float f){ u32 u=__float_as_uint(f); return (u16)((u+0x7fffu+((u>>16)&1u))>>16); }

// async global->LDS, 16B/lane. LDS dest is wave-uniform base + lane*16 (m97 pattern).
__device__ __forceinline__ void gl2lds(const u16* g, u16* l){
  __builtin_amdgcn_global_load_lds((const __attribute__((address_space(1))) u32*)g,
                                   (__attribute__((address_space(3))) u32*)l, 16, 0, 0);
}
__device__ __forceinline__ void stc(u16* p, float v){ *p = f2bf(v); }
__device__ __forceinline__ void stc(float* p, float v){ *p = v; }
__device__ __forceinline__ void ld4(const float* p, float* v){ float4 x=*(const float4*)p; v[0]=x.x;v[1]=x.y;v[2]=x.z;v[3]=x.w; }
__device__ __forceinline__ void ld4(const u16* p, float* v){ ushort4 x=*(const ushort4*)p; v[0]=bf2f(x.x);v[1]=bf2f(x.y);v[2]=bf2f(x.z);v[3]=bf2f(x.w); }

// XCD-aware bijective block remap (T1, m204 form). Requires nwg % 8 == 0.
__device__ __forceinline__ int xcd_remap(){
  int gx = gridDim.x, gy = gridDim.y;
  int lin = blockIdx.x + gx*(blockIdx.y + gy*blockIdx.z);
  int nwg = gx*gy*gridDim.z;
  if (nwg & 7) return lin;
  int q = nwg >> 3;
  return (lin & 7)*q + (lin >> 3);
}

// ---- prep: cvt weights to bf16 + zero norms (one dispatch) ----
__global__ void prep_kernel(const float* __restrict__ qkv_w, const float* __restrict__ proj_w,
                            u16* __restrict__ wq, u16* __restrict__ wp, float* __restrict__ norms){
  int i = blockIdx.x*256 + threadIdx.x;
  if (i < 110592) wq[i] = f2bf(qkv_w[i]);
  else if (i < 147456) wp[i-110592] = f2bf(proj_w[i-110592]);
  else if (i < 156672) norms[i-147456] = 0.f;
}

// ---- tiled transpose: in [z][192][in_pitch] (TIN) -> out [z][cols][192] bf16 ----
template<typename TIN>
__global__ __launch_bounds__(256) void transpose_kernel(
    const TIN* __restrict__ in, u16* __restrict__ out,
    long in_hi, long in_lo, long out_slab, int in_pitch)
{
  __shared__ float tile[64][65];
  const int t = threadIdx.x;
  const int z = blockIdx.z;
  const TIN* ip = in + (long)(z>>3)*in_hi + (long)(z&7)*in_lo;
  u16* op = out + (long)z*out_slab;
  const int s0 = blockIdx.x*64, c0 = blockIdx.y*64;
  const int rl = t>>4, cc = (t&15)*4;
#pragma unroll
  for (int rr=0; rr<4; rr++){
    int row = rr*16 + rl;
    float v[4];
    ld4(ip + (long)(c0+row)*in_pitch + s0 + cc, v);
    tile[row][cc+0]=v[0]; tile[row][cc+1]=v[1]; tile[row][cc+2]=v[2]; tile[row][cc+3]=v[3];
  }
  __syncthreads();
#pragma unroll
  for (int wr=0; wr<4; wr++){
    int sl = wr*16 + rl;
    ushort4 s;
    s.x = f2bf(tile[cc+0][sl]); s.y = f2bf(tile[cc+1][sl]);
    s.z = f2bf(tile[cc+2][sl]); s.w = f2bf(tile[cc+3][sl]);
    *(ushort4*)(op + (long)(s0+sl)*192 + c0 + cc) = s;
  }
}

// ---- NT MFMA GEMM: C[m][n] = sum_k A[m][k]*B[n][k]; K=192, lda=ldb=192, ldc=65536
template<typename TC>
__global__ __launch_bounds__(256) void gemm_nt_kernel(
    const u16* __restrict__ A, const u16* __restrict__ B, TC* __restrict__ C,
    int M, long sB, long sC)
{
  __shared__ __align__(16) u16 As[128*32];
  __shared__ __align__(16) u16 Bs[128*32];
  const int t = threadIdx.x, w = t>>6, l = t&63;
  const int wrk = xcd_remap();
  const int mt = wrk % gridDim.x;
  const int rest = wrk / gridDim.x;
  const int nt = rest % gridDim.y, bz = rest / gridDim.y;
  const int m0 = mt*128, n0 = nt*128;
  const u16* Bb = B + (long)bz*sB + (long)n0*192;
  const int rq = t>>2, qq = (t&3)*8;
  int ar0 = m0 + rq;      if (ar0 >= M) ar0 = M-1;
  int ar1 = m0 + 64 + rq; if (ar1 >= M) ar1 = M-1;
  f32x4 acc[4][4];
#pragma unroll
  for (int i=0;i<4;i++)
#pragma unroll
    for (int j=0;j<4;j++) acc[i][j] = f32x4{0.f,0.f,0.f,0.f};

  for (int k0=0; k0<192; k0+=32){
    __syncthreads();
    gl2lds(A + (long)ar0*192 + k0 + qq, As + t*8);
    gl2lds(A + (long)ar1*192 + k0 + qq, As + (256+t)*8);
    gl2lds(Bb + (long)rq*192 + k0 + qq, Bs + t*8);
    gl2lds(Bb + (long)(64+rq)*192 + k0 + qq, Bs + (256+t)*8);
    __syncthreads();
    const u16* ap = As + ((w>>1)*64 + (l&15))*32 + (l>>4)*8;
    const u16* bp = Bs + ((w&1)*64 + (l&15))*32 + (l>>4)*8;
    bf16x8 a[4], b[4];
#pragma unroll
    for (int i=0;i<4;i++){ a[i] = *(const bf16x8*)(ap + i*512); b[i] = *(const bf16x8*)(bp + i*512); }
#pragma unroll
    for (int i=0;i<4;i++)
#pragma unroll
      for (int j=0;j<4;j++) acc[i][j] = MFMA16(a[i], b[j], acc[i][j]);
  }
  const int mw = m0 + (w>>1)*64, nw = n0 + (w&1)*64;
  TC* Cb = C + (long)bz*sC;
#pragma unroll
  for (int i=0;i<4;i++){
#pragma unroll
    for (int r=0;r<4;r++){
      int row = mw + i*16 + (l>>4)*4 + r;
      if (row < M){
        TC* cp = Cb + (long)row*65536 + nw + (l&15);
#pragma unroll
        for (int j=0;j<4;j++) stc(cp + j*16, acc[i][j][r]);
      }
    }
  }
}

// ---- depthwise 3x3 + fused sum-of-squares, register-streaming v3.
// One wave = full image row (64 lanes x 4 cols), 16 output rows/wave.
// One-row software prefetch: row g+1's load issues before row g's compute,
// so 2 loads in flight per wave. Low VGPR (~50) -> high occupancy.
__global__ __launch_bounds__(256) void dwconv_kernel(
    const u16* __restrict__ in, const float* __restrict__ w9s,
    u16* __restrict__ out, float* __restrict__ norms)
{
  const int bo = blockIdx.x >> 2;   // channel slab (b*576 + o)
  const int rg = blockIdx.x & 3;    // 64-row group
  const int o  = bo % 576;
  const int t = threadIdx.x, wv = t>>6, l = t&63;
  const u16* ip = in + (long)bo*65536L + l*4;
  u16* op = out + (long)bo*65536L + l*4;
  float w[9];
#pragma unroll
  for (int i=0;i<9;i++) w[i] = w9s[o*9+i];
  const int r0 = rg*64 + wv*16;   // first output row of this wave
  float ap0=0.f,ap1=0.f,ap2=0.f,ap3=0.f;   // out row g-1 (completing)
  float ac0=0.f,ac1=0.f,ac2=0.f,ac3=0.f;   // out row g
  float ss = 0.f;
  float v0,v1,v2,v3;
  // preload first input row (g = r0-1)
  if (r0 >= 1){
    ushort4 u = *(const ushort4*)(ip + (r0-1)*256);
    v0=bf2f(u.x); v1=bf2f(u.y); v2=bf2f(u.z); v3=bf2f(u.w);
  } else { v0=0.f; v1=0.f; v2=0.f; v3=0.f; }
#pragma unroll
  for (int it=0; it<18; ++it){
    const int g = r0 - 1 + it;       // input row being processed
    // prefetch row g+1 (in flight under this iteration's compute)
    float p0,p1,p2,p3;
    if (it < 17 && g+1 < 256){
      ushort4 u = *(const ushort4*)(ip + (g+1)*256);
      p0=bf2f(u.x); p1=bf2f(u.y); p2=bf2f(u.z); p3=bf2f(u.w);
    } else { p0=0.f; p1=0.f; p2=0.f; p3=0.f; }
    float slv = __shfl(v3, (l+63)&63);
    float srv = __shfl(v0, (l+1)&63);
    const float lf  = (l==0)  ? 0.f : slv;
    const float rgt = (l==63) ? 0.f : srv;
    // weight row 2 completes output row g-1
    ap0 = fmaf(w[6],lf, fmaf(w[7],v0, fmaf(w[8],v1, ap0)));
    ap1 = fmaf(w[6],v0, fmaf(w[7],v1, fmaf(w[8],v2, ap1)));
    ap2 = fmaf(w[6],v1, fmaf(w[7],v2, fmaf(w[8],v3, ap2)));
    ap3 = fmaf(w[6],v2, fmaf(w[7],v3, fmaf(w[8],rgt, ap3)));
    if (it >= 2){
      ushort4 s;
      s.x = f2bf(ap0); s.y = f2bf(ap1); s.z = f2bf(ap2); s.w = f2bf(ap3);
      *(ushort4*)(op + (g-1)*256) = s;
      ss = fmaf(ap0,ap0, fmaf(ap1,ap1, fmaf(ap2,ap2, fmaf(ap3,ap3, ss))));
    }
    // weight row 1 into output row g
    ac0 = fmaf(w[3],lf, fmaf(w[4],v0, fmaf(w[5],v1, ac0)));
    ac1 = fmaf(w[3],v0, fmaf(w[4],v1, fmaf(w[5],v2, ac1)));
    ac2 = fmaf(w[3],v1, fmaf(w[4],v2, fmaf(w[5],v3, ac2)));
    ac3 = fmaf(w[3],v2, fmaf(w[4],v3, fmaf(w[5],rgt, ac3)));
    // weight row 0 starts output row g+1; rotate pipeline
    ap0=ac0; ap1=ac1; ap2=ac2; ap3=ac3;
    ac0 = fmaf(w[0],lf, fmaf(w[1],v0, w[2]*v1));
    ac1 = fmaf(w[0],v0, fmaf(w[1],v1, w[2]*v2));
    ac2 = fmaf(w[0],v1, fmaf(w[1],v2, w[2]*v3));
    ac3 = fmaf(w[0],v2, fmaf(w[1],v3, w[2]*rgt));
    v0=p0; v1=p1; v2=p2; v3=p3;
  }
  // per-wave sum-of-squares -> norms (Q/K channels only)
#pragma unroll
  for (int off=32; off>=1; off>>=1) ss += __shfl_xor(ss, off);
  if (o < 384 && l == 0){
    atomicAdd(&norms[bo*8 + (r0>>5)], ss);
  }
}

// ---- QK^T MFMA, K-split partials ----
__global__ __launch_bounds__(256) void gemm_qk_kernel(
    const u16* __restrict__ conv, float* __restrict__ part)
{
  __shared__ __align__(16) u16 As[64*64];
  __shared__ __align__(16) u16 Bs[64*64];
  const int t = threadIdx.x, w = t>>6, l = t&63;
  const int wrk = xcd_remap();
  const int mt = wrk % 3;
  const int rest = wrk / 3;
  const int nt = rest % 3, z = rest / 3;
  const int bh = z>>3, sl = z&7;
  const int b = bh>>3, h = bh&7;
  const u16* Q  = conv + (long)b*37748736L + (long)h*1572864L;
  const u16* Kp = Q + 12582912L;
  const int m0 = mt*64, n0 = nt*64;
  const int rq = t>>3, qq = (t&7)*8;
  const long qo0 = (long)(m0+rq)*8192 + qq;
  const long qo1 = (long)(m0+32+rq)*8192 + qq;
  const long ko0 = (long)(n0+rq)*8192 + qq;
  const long ko1 = (long)(n0+32+rq)*8192 + qq;
  f32x4 acc[2][2];
#pragma unroll
  for (int i=0;i<2;i++)
#pragma unroll
    for (int j=0;j<2;j++) acc[i][j] = f32x4{0.f,0.f,0.f,0.f};
  const int kbeg = sl*1024;
  for (int k0=kbeg; k0<kbeg+1024; k0+=64){
    __syncthreads();
    gl2lds(Q  + qo0 + k0, As + t*8);
    gl2lds(Q  + qo1 + k0, As + (256+t)*8);
    gl2lds(Kp + ko0 + k0, Bs + t*8);
    gl2lds(Kp + ko1 + k0, Bs + (256+t)*8);
    __syncthreads();
    const u16* ap = As + ((w>>1)*32 + (l&15))*64 + (l>>4)*8;
    const u16* bp = Bs + ((w&1)*32 + (l&15))*64 + (l>>4)*8;
#pragma unroll
    for (int ks=0; ks<2; ks++){
      bf16x8 a0 = *(const bf16x8*)(ap + ks*32);
      bf16x8 a1 = *(const bf16x8*)(ap + 1024 + ks*32);
      bf16x8 b0 = *(const bf16x8*)(bp + ks*32);
      bf16x8 b1 = *(const bf16x8*)(bp + 1024 + ks*32);
      acc[0][0]=MFMA16(a0,b0,acc[0][0]); acc[0][1]=MFMA16(a0,b1,acc[0][1]);
      acc[1][0]=MFMA16(a1,b0,acc[1][0]); acc[1][1]=MFMA16(a1,b1,acc[1][1]);
    }
  }
  float* P = part + (long)z*36864L;
  const int mw = m0 + (w>>1)*32, nw = n0 + (w&1)*32;
#pragma unroll
  for (int i=0;i<2;i++)
#pragma unroll
    for (int j=0;j<2;j++)
#pragma unroll
      for (int r=0;r<4;r++)
        P[(long)(mw + i*16 + (l>>4)*4 + r)*192 + nw + j*16 + (l&15)] = acc[i][j][r];
}

// ---- reduce partials + l2norm scales + temperature + softmax -> attn bf16 ----
// 256 threads = 4 independent waves, one attn row each.
__global__ __launch_bounds__(256) void softmax_kernel(
    const float* __restrict__ part, const float* __restrict__ temp,
    const float* __restrict__ norms, u16* __restrict__ attn)
{
  const int t = threadIdx.x, wv = t>>6, l = t&63;
  const int rg = blockIdx.x*4 + wv;
  const int bh = rg/192, r = rg - bh*192;
  const int b = bh>>3, h = bh&7;
  const float tp = temp[h];
  const float sq = norms[(b*576 + 24*h + (r>>3))*8 + (r&7)];
  const float invq = 1.f/fmaxf(sqrtf(sq), 1e-12f);
  const float* P = part + (long)bh*8L*36864L + (long)r*192;
  float lv[3];
#pragma unroll
  for (int j=0;j<3;j++){
    int col = l + j*64;
    float s = 0.f;
#pragma unroll
    for (int ks=0; ks<8; ks++) s += P[(long)ks*36864L + col];
    float sk = norms[(b*576 + 192 + 24*h + (col>>3))*8 + (col&7)];
    float invk = 1.f/fmaxf(sqrtf(sk), 1e-12f);
    lv[j] = s*invq*invk*tp;
  }
  float mx = fmaxf(lv[0], fmaxf(lv[1], lv[2]));
#pragma unroll
  for (int o=32;o>=1;o>>=1) mx = fmaxf(mx, __shfl_xor(mx, o));
  float e[3], sum = 0.f;
#pragma unroll
  for (int j=0;j<3;j++){ e[j] = expf(lv[j]-mx); sum += e[j]; }
#pragma unroll
  for (int o=32;o>=1;o>>=1) sum += __shfl_xor(sum, o);
  const float inv = 1.f/sum;
  u16* ap = attn + (long)bh*36864L + (long)r*192;
#pragma unroll
  for (int j=0;j<3;j++) ap[l + j*64] = f2bf(e[j]*inv);
}

// ---- attn@V with LDS-bounce epilogue -> out_sc[s][C] ----
__global__ __launch_bounds__(256) void gemm_av_kernel(
    const u16* __restrict__ VT, const u16* __restrict__ attn, u16* __restrict__ out_sc)
{
  __shared__ __align__(16) char smem[69632];
  u16* As = (u16*)smem;
  u16* Bs = (u16*)(smem + 8192);
  const int t = threadIdx.x, w = t>>6, l = t&63;
  const int wrk = xcd_remap();
  const int mt = wrk % 64;
  const int rest = wrk / 64;
  const int nt = rest % 2, bh = rest / 2;
  const int b = bh>>3, h = bh&7;
  const u16* Av = VT + (long)bh*1572864L;
  const u16* Bt = attn + (long)bh*36864L;
  const int m0 = mt*128, n0 = nt*128;
  const int rq = t>>2, qq = (t&3)*8;
  int br0 = n0 + rq;      if (br0 > 191) br0 = 191;
  int br1 = n0 + 64 + rq; if (br1 > 191) br1 = 191;
  f32x4 acc[4][4];
#pragma unroll
  for (int i=0;i<4;i++)
#pragma unroll
    for (int j=0;j<4;j++) acc[i][j] = f32x4{0.f,0.f,0.f,0.f};
  for (int k0=0; k0<192; k0+=32){
    __syncthreads();
    gl2lds(Av + (long)(m0+rq)*192 + k0 + qq, As + t*8);
    gl2lds(Av + (long)(m0+64+rq)*192 + k0 + qq, As + (256+t)*8);
    gl2lds(Bt + (long)br0*192 + k0 + qq, Bs + t*8);
    gl2lds(Bt + (long)br1*192 + k0 + qq, Bs + (256+t)*8);
    __syncthreads();
    const u16* ap = As + ((w>>1)*64 + (l&15))*32 + (l>>4)*8;
    const u16* bp = Bs + ((w&1)*64 + (l&15))*32 + (l>>4)*8;
    bf16x8 a[4], bb[4];
#pragma unroll
    for (int i=0;i<4;i++){ a[i] = *(const bf16x8*)(ap + i*512); bb[i] = *(const bf16x8*)(bp + i*512); }
#pragma unroll
    for (int i=0;i<4;i++)
#pragma unroll
      for (int j=0;j<4;j++) acc[i][j] = MFMA16(a[i], bb[j], acc[i][j]);
  }
  __syncthreads();
  float* wb = (float*)smem + w*4352;
#pragma unroll
  for (int i=0;i<4;i++)
#pragma unroll
    for (int j=0;j<4;j++)
#pragma unroll
      for (int r=0;r<4;r++)
        wb[(i*16 + (l>>4)*4 + r)*68 + j*16 + (l&15)] = acc[i][j][r];
  __syncthreads();
  const int c0w = nt*128 + (w&1)*64;
  if (c0w < 192){
    const int cb = 24*h + (c0w>>3);
    const int mw = m0 + (w>>1)*64;
    u16* ob = out_sc + (long)b*12582912L + cb;
    const int nl0 = l>>3, sb = l&7;
#pragma unroll
    for (int ri=0; ri<8; ri++){
      int nl = ri*8 + nl0;
      const float* src = wb + nl*68 + sb;
      u32 d0 = (u32)f2bf(src[0])  | ((u32)f2bf(src[8])  << 16);
      u32 d1 = (u32)f2bf(src[16]) | ((u32)f2bf(src[24]) << 16);
      u32 d2 = (u32)f2bf(src[32]) | ((u32)f2bf(src[40]) << 16);
      u32 d3 = (u32)f2bf(src[48]) | ((u32)f2bf(src[56]) << 16);
      *(uint4*)(ob + ((long)sb*8192 + mw + nl)*192) = make_uint4(d0,d1,d2,d3);
    }
  }
}

extern "C" void kernel_launch(void* const* d_in, const int* in_sizes, int n_in,
                              void* d_out, int out_size, void* d_ws, size_t ws_size,
                              hipStream_t stream)
{
  const float* x      = (const float*)d_in[0];
  const float* qkv_w  = (const float*)d_in[1];
  const float* dw_w   = (const float*)d_in[2];
  const float* proj_w = (const float*)d_in[3];
  const float* temp   = (const float*)d_in[4];
  float* out = (float*)d_out;

  // workspace layout. qkv_raw live in [150994944, 301989888) until dwconv done;
  // VT/out_sc/part/attn reuse that range after. wq/wp/norms live across the qkv
  // GEMM -> placed PAST 301989888 (aliasing here was the round-2/3 NaN bug).
  char* ws = (char*)d_ws;
  u16*   xT      = (u16*)(ws + 0);
  u16*   conv    = (u16*)(ws + 0);
  u16*   qkv_raw = (u16*)(ws + 150994944);
  u16*   VT      = (u16*)(ws + 150994944);
  u16*   out_sc  = (u16*)(ws + 201326592);
  float* part    = (float*)(ws + 251658240);
  u16*   attn    = (u16*)(ws + 270532608);
  u16*   wq_bf   = (u16*)(ws + 301989888);
  u16*   wp_bf   = (u16*)(ws + 302211072);
  float* norms   = (float*)(ws + 302284800);

  prep_kernel<<<dim3(612), 256, 0, stream>>>(qkv_w, proj_w, wq_bf, wp_bf, norms);

  // xT[b][s][c] = x[b][c][s]
  transpose_kernel<float><<<dim3(1024, 3, 2), 256, 0, stream>>>(
      x, xT, 0L, 12582912L, 12582912L, 65536);

  // qkv_raw = qkv_w @ x  (NT vs xT), M=576
  gemm_nt_kernel<u16><<<dim3(5, 512, 2), 256, 0, stream>>>(
      wq_bf, xT, qkv_raw, 576, 12582912L, 37748736L);

  // depthwise 3x3 + q/k sum-of-squares (register-streaming v3, prefetch)
  dwconv_kernel<<<dim3(1152*4), 256, 0, stream>>>(qkv_raw, dw_w, conv, norms);

  // VT[bh][n][d] = Vslab[d][n]
  transpose_kernel<u16><<<dim3(128, 3, 16), 256, 0, stream>>>(
      conv + 25165824L, VT, 37748736L, 1572864L, 1572864L, 8192);

  // raw QK^T partials
  gemm_qk_kernel<<<dim3(3, 3, 128), 256, 0, stream>>>(conv, part);

  // reduce + normalize + temperature + softmax -> attn (bf16)
  softmax_kernel<<<dim3(768), 256, 0, stream>>>(part, temp, norms, attn);

  // attn @ V -> out_sc [b][s][C]
  gemm_av_kernel<<<dim3(64, 2, 16), 256, 0, stream>>>(VT, attn, out_sc);

  // out = proj_w @ attn_out (NT vs out_sc), M=192, fp32 out
  gemm_nt_kernel<float><<<dim3(2, 512, 2), 256, 0, stream>>>(
      wp_bf, out_sc, out, 192, 12582912L, 12582912L);
}